// Round 1
// baseline (267.124 us; speedup 1.0000x reference)
//
#include <hip/hip_runtime.h>

#define D_DIM   1024
#define PER_LANE 16   // D / 64
#define NLAYER   2
#define NPAIR    8    // ent pairs per lane

__global__ void qent_kernel(const float* __restrict__ x,
                            const float* __restrict__ local_angles,  // [2][1024]
                            const float* __restrict__ ent_angles,    // [2][512]
                            float* __restrict__ out, int B)
{
    const int lane  = threadIdx.x & 63;
    const int wid   = threadIdx.x >> 6;
    const int wpb   = blockDim.x >> 6;
    const int gwave = blockIdx.x * wpb + wid;
    const int nwave = gridDim.x * wpb;

    // Transposed [layer][step][lane] so per-lane reads are conflict-free.
    __shared__ float lds_cl[NLAYER][PER_LANE][64];
    __shared__ float lds_sl[NLAYER][PER_LANE][64];
    __shared__ float lds_ce[NLAYER][NPAIR][64];
    __shared__ float lds_se[NLAYER][NPAIR][64];

    for (int idx = threadIdx.x; idx < NLAYER * D_DIM; idx += blockDim.x) {
        int L = idx >> 10, i = idx & (D_DIM - 1);
        int ln = i >> 4, k = i & 15;
        float s, c;
        sincosf(local_angles[idx], &s, &c);
        lds_cl[L][k][ln] = c;
        lds_sl[L][k][ln] = s;
    }
    for (int idx = threadIdx.x; idx < NLAYER * (D_DIM / 2); idx += blockDim.x) {
        int L = idx >> 9, p = idx & (D_DIM / 2 - 1);
        int ln = p >> 3, m = p & 7;
        float s, c;
        sincosf(ent_angles[idx], &s, &c);
        lds_ce[L][m][ln] = c;
        lds_se[L][m][ln] = s;
    }
    __syncthreads();

    // Hoist angle tables to registers (row-invariant, reused across rows).
    float cl[NLAYER][PER_LANE], sl[NLAYER][PER_LANE];
    float ce[NLAYER][NPAIR],    se[NLAYER][NPAIR];
    #pragma unroll
    for (int L = 0; L < NLAYER; ++L) {
        #pragma unroll
        for (int k = 0; k < PER_LANE; ++k) {
            cl[L][k] = lds_cl[L][k][lane];
            sl[L][k] = lds_sl[L][k][lane];
        }
        #pragma unroll
        for (int m = 0; m < NPAIR; ++m) {
            ce[L][m] = lds_ce[L][m][lane];
            se[L][m] = lds_se[L][m][lane];
        }
    }

    for (int row = gwave; row < B; row += nwave) {
        const float4* src =
            reinterpret_cast<const float4*>(x + (size_t)row * D_DIM + lane * PER_LANE);
        float v[PER_LANE];
        #pragma unroll
        for (int q = 0; q < 4; ++q) {
            float4 t = src[q];
            v[4*q+0] = t.x; v[4*q+1] = t.y; v[4*q+2] = t.z; v[4*q+3] = t.w;
        }

        #pragma unroll
        for (int L = 0; L < NLAYER; ++L) {
            // ---------- local chain: u_{i+1} = s_i u_i + c_i v_{i+1} ----------
            float vnf = __shfl_down(v[0], 1);  // lane l+1's ORIGINAL v[0]

            // pass 1: this lane's composed affine map (A, B): u_out = A*u_in + B
            float A = 1.f, Bv = 0.f;
            #pragma unroll
            for (int k = 0; k < PER_LANE; ++k) {
                float vn = (k < PER_LANE - 1) ? v[k + 1] : vnf;
                Bv = sl[L][k] * Bv + cl[L][k] * vn;
                A  = sl[L][k] * A;
            }

            // inclusive Hillis-Steele affine scan across 64 lanes
            float Ai = A, Bi = Bv;
            #pragma unroll
            for (int dd = 1; dd < 64; dd <<= 1) {
                float Au = __shfl_up(Ai, dd);
                float Bu = __shfl_up(Bi, dd);
                if (lane >= dd) {
                    Bi = Ai * Bu + Bi;   // apply earlier segment first
                    Ai = Ai * Au;
                }
            }
            // exclusive shift; u entering this lane's first step
            float Ax  = __shfl_up(Ai, 1);
            float Bx  = __shfl_up(Bi, 1);
            float v0b = __shfl(v[0], 0);
            float u   = (lane == 0) ? v[0] : (Ax * v0b + Bx);

            // replay: finals f_i = c_i u_i - s_i v_{i+1}
            #pragma unroll
            for (int k = 0; k < PER_LANE - 1; ++k) {
                float vn = v[k + 1];
                float f  = cl[L][k] * u - sl[L][k] * vn;
                u        = sl[L][k] * u + cl[L][k] * vn;
                v[k] = f;
            }
            // wrap step i = D-1 uses a0 = provisional f_0 (lane 0, written at k=0)
            float a0   = __shfl(v[0], 0);
            float vn15 = (lane == 63) ? a0 : vnf;
            float f15  = cl[L][PER_LANE-1] * u - sl[L][PER_LANE-1] * vn15;
            float un   = sl[L][PER_LANE-1] * u + cl[L][PER_LANE-1] * vn15;
            v[PER_LANE-1] = f15;
            float f0new = __shfl(un, 63);   // lane 63's un is the final f_0
            if (lane == 0) v[0] = f0new;

            // ---------- ent layer: disjoint pairs, lane-local ----------
            #pragma unroll
            for (int m = 0; m < NPAIR; ++m) {
                float x0 = v[2*m], x1 = v[2*m+1];
                v[2*m]   = ce[L][m] * x0 - se[L][m] * x1;
                v[2*m+1] = se[L][m] * x0 + ce[L][m] * x1;
            }
        }

        float4* dst =
            reinterpret_cast<float4*>(out + (size_t)row * D_DIM + lane * PER_LANE);
        #pragma unroll
        for (int q = 0; q < 4; ++q) {
            float4 t;
            t.x = v[4*q+0]; t.y = v[4*q+1]; t.z = v[4*q+2]; t.w = v[4*q+3];
            dst[q] = t;
        }
    }
}

extern "C" void kernel_launch(void* const* d_in, const int* in_sizes, int n_in,
                              void* d_out, int out_size, void* d_ws, size_t ws_size,
                              hipStream_t stream) {
    const float* x  = (const float*)d_in[0];
    const float* la = (const float*)d_in[1];
    const float* ea = (const float*)d_in[2];
    float* out = (float*)d_out;
    int B = in_sizes[0] / D_DIM;   // 32768
    qent_kernel<<<1024, 256, 0, stream>>>(x, la, ea, out, B);
}

// Round 2
// 67.128 us; speedup vs baseline: 3.9793x; 3.9793x over previous
//
#include <hip/hip_runtime.h>

#define D_DIM    1024
#define PER_LANE 16   // D / 64
#define NLAYER   2
#define NPAIR    8    // ent pairs per lane
#define WPB      4    // waves per block (blockDim = 256)

// XOR swizzle over 16B chunk index: bijective involution, makes both the
// coalesced phase (chunks q*64+l) and the segment phase (chunks 4l+r)
// uniform across the 8 LDS bank-groups.
__device__ __forceinline__ int swz(int c) { return c ^ ((c >> 3) & 7); }

__global__ __launch_bounds__(256) void qent_kernel(
        const float* __restrict__ x,
        const float* __restrict__ local_angles,  // [2][1024]
        const float* __restrict__ ent_angles,    // [2][512]
        float* __restrict__ out, int B)
{
    const int lane  = threadIdx.x & 63;
    const int wid   = threadIdx.x >> 6;
    const int gwave = blockIdx.x * WPB + wid;
    const int nwave = gridDim.x * WPB;

    // Angle tables, transposed [layer][step][lane] -> conflict-free reads.
    __shared__ float lds_cl[NLAYER][PER_LANE][64];
    __shared__ float lds_sl[NLAYER][PER_LANE][64];
    __shared__ float lds_ce[NLAYER][NPAIR][64];
    __shared__ float lds_se[NLAYER][NPAIR][64];
    // Per-wave transpose buffer: 256 chunks of 16B = 4 KB.
    __shared__ float4 tb[WPB][256];

    for (int idx = threadIdx.x; idx < NLAYER * D_DIM; idx += blockDim.x) {
        int L = idx >> 10, i = idx & (D_DIM - 1);
        int ln = i >> 4, k = i & 15;
        float s, c;
        sincosf(local_angles[idx], &s, &c);
        lds_cl[L][k][ln] = c;
        lds_sl[L][k][ln] = s;
    }
    for (int idx = threadIdx.x; idx < NLAYER * (D_DIM / 2); idx += blockDim.x) {
        int L = idx >> 9, p = idx & (D_DIM / 2 - 1);
        int ln = p >> 3, m = p & 7;
        float s, c;
        sincosf(ent_angles[idx], &s, &c);
        lds_ce[L][m][ln] = c;
        lds_se[L][m][ln] = s;
    }
    __syncthreads();

    float cl[NLAYER][PER_LANE], sl[NLAYER][PER_LANE];
    float ce[NLAYER][NPAIR],    se[NLAYER][NPAIR];
    #pragma unroll
    for (int L = 0; L < NLAYER; ++L) {
        #pragma unroll
        for (int k = 0; k < PER_LANE; ++k) {
            cl[L][k] = lds_cl[L][k][lane];
            sl[L][k] = lds_sl[L][k][lane];
        }
        #pragma unroll
        for (int m = 0; m < NPAIR; ++m) {
            ce[L][m] = lds_ce[L][m][lane];
            se[L][m] = lds_se[L][m][lane];
        }
    }

    for (int row = gwave; row < B; row += nwave) {
        // ---- coalesced load: lane l gets 16B at base + q*1KB + l*16 ----
        const float4* rp =
            reinterpret_cast<const float4*>(x + (size_t)row * D_DIM);
        float4 ld[4];
        #pragma unroll
        for (int q = 0; q < 4; ++q) ld[q] = rp[q * 64 + lane];
        #pragma unroll
        for (int q = 0; q < 4; ++q) tb[wid][swz(q * 64 + lane)] = ld[q];

        // ---- segment read: lane l owns columns [16l, 16l+16) ----
        float v[PER_LANE];
        #pragma unroll
        for (int r = 0; r < 4; ++r) {
            float4 t = tb[wid][swz(4 * lane + r)];
            v[4*r+0] = t.x; v[4*r+1] = t.y; v[4*r+2] = t.z; v[4*r+3] = t.w;
        }

        #pragma unroll
        for (int L = 0; L < NLAYER; ++L) {
            // ---------- local chain: u_{i+1} = s_i u_i + c_i v_{i+1} ----------
            float vnf = __shfl_down(v[0], 1);  // lane l+1's ORIGINAL v[0]

            // pass 1: this lane's composed affine map (A, B)
            float A = 1.f, Bv = 0.f;
            #pragma unroll
            for (int k = 0; k < PER_LANE; ++k) {
                float vn = (k < PER_LANE - 1) ? v[k + 1] : vnf;
                Bv = sl[L][k] * Bv + cl[L][k] * vn;
                A  = sl[L][k] * A;
            }

            // inclusive Hillis-Steele affine scan across 64 lanes
            float Ai = A, Bi = Bv;
            #pragma unroll
            for (int dd = 1; dd < 64; dd <<= 1) {
                float Au = __shfl_up(Ai, dd);
                float Bu = __shfl_up(Bi, dd);
                if (lane >= dd) {
                    Bi = Ai * Bu + Bi;
                    Ai = Ai * Au;
                }
            }
            float Ax  = __shfl_up(Ai, 1);
            float Bx  = __shfl_up(Bi, 1);
            float v0b = __shfl(v[0], 0);
            float u   = (lane == 0) ? v[0] : (Ax * v0b + Bx);

            // replay: finals f_i = c_i u_i - s_i v_{i+1}
            #pragma unroll
            for (int k = 0; k < PER_LANE - 1; ++k) {
                float vn = v[k + 1];
                float f  = cl[L][k] * u - sl[L][k] * vn;
                u        = sl[L][k] * u + cl[L][k] * vn;
                v[k] = f;
            }
            // wrap step i = D-1 uses a0 = provisional f_0 (lane 0)
            float a0   = __shfl(v[0], 0);
            float vn15 = (lane == 63) ? a0 : vnf;
            float f15  = cl[L][PER_LANE-1] * u - sl[L][PER_LANE-1] * vn15;
            float un   = sl[L][PER_LANE-1] * u + cl[L][PER_LANE-1] * vn15;
            v[PER_LANE-1] = f15;
            float f0new = __shfl(un, 63);
            if (lane == 0) v[0] = f0new;

            // ---------- ent layer: disjoint pairs, lane-local ----------
            #pragma unroll
            for (int m = 0; m < NPAIR; ++m) {
                float x0 = v[2*m], x1 = v[2*m+1];
                v[2*m]   = ce[L][m] * x0 - se[L][m] * x1;
                v[2*m+1] = se[L][m] * x0 + ce[L][m] * x1;
            }
        }

        // ---- segment write back to LDS ----
        #pragma unroll
        for (int r = 0; r < 4; ++r) {
            float4 t;
            t.x = v[4*r+0]; t.y = v[4*r+1]; t.z = v[4*r+2]; t.w = v[4*r+3];
            tb[wid][swz(4 * lane + r)] = t;
        }
        // ---- coalesced store ----
        float4* op = reinterpret_cast<float4*>(out + (size_t)row * D_DIM);
        float4 st[4];
        #pragma unroll
        for (int q = 0; q < 4; ++q) st[q] = tb[wid][swz(q * 64 + lane)];
        #pragma unroll
        for (int q = 0; q < 4; ++q) op[q * 64 + lane] = st[q];
    }
}

extern "C" void kernel_launch(void* const* d_in, const int* in_sizes, int n_in,
                              void* d_out, int out_size, void* d_ws, size_t ws_size,
                              hipStream_t stream) {
    const float* x  = (const float*)d_in[0];
    const float* la = (const float*)d_in[1];
    const float* ea = (const float*)d_in[2];
    float* out = (float*)d_out;
    int B = in_sizes[0] / D_DIM;   // 32768
    qent_kernel<<<2048, 256, 0, stream>>>(x, la, ea, out, B);
}